// Round 1
// baseline (428.011 us; speedup 1.0000x reference)
//
#include <hip/hip_runtime.h>

// NeighbourChannels: out[b,c,hw] = (sum_c' x[b,c',hw]) - x[b,c,hw]
// x: fp32 [B=16, C=256, H=128, W=128], HW = 16384.
//
// Single-pass design: each block stages C=256 channels x POS=64 hw positions
// (64 KiB) into LDS with float4 loads, accumulating channel partial sums in
// registers on the way in. LDS reduce of 16 partials -> per-position totals,
// then write phase emits total - x from LDS. Each element: 1 HBM read,
// 1 HBM write (the 512 MiB minimum).

#define NC_C   256
#define NC_HW  16384
#define NC_POS 64      // hw positions per block (64 floats = 16 float4)
#define NC_NT  256     // threads per block

__global__ __launch_bounds__(NC_NT, 2)
void neighbour_channels_kernel(const float* __restrict__ x,
                               float* __restrict__ out) {
    __shared__ float  tile[NC_C][NC_POS];   // 64 KiB staged input
    __shared__ float4 psum[16][16];         // [channel-group][pos-group] partials
    __shared__ float4 sums[16];             // per pos-group channel totals

    const int t  = threadIdx.x;
    const int pg = t & 15;                  // float4 position group 0..15
    const int cg = t >> 4;                  // channel group 0..15

    // blockIdx: b = blk / (HW/POS), chunk = blk % (HW/POS); HW/POS = 256.
    const int b     = blockIdx.x >> 8;
    const int chunk = blockIdx.x & 255;
    const long long base = ((long long)b * NC_C) * NC_HW
                         + (long long)chunk * NC_POS;

    const float4* xin = (const float4*)(x + base);  // +c*(HW/4) per channel

    // ---- load phase: 16 iterations, each thread loads 1 float4/channel ----
    float4 acc = make_float4(0.f, 0.f, 0.f, 0.f);
    #pragma unroll
    for (int i = 0; i < 16; ++i) {
        const int c = i * 16 + cg;
        float4 v = xin[(long long)c * (NC_HW / 4) + pg];
        acc.x += v.x; acc.y += v.y; acc.z += v.z; acc.w += v.w;
        *(float4*)&tile[c][pg * 4] = v;
    }
    psum[cg][pg] = acc;
    __syncthreads();

    // ---- reduce 16 channel-group partials per position group ----
    if (t < 16) {
        float4 s = psum[0][t];
        #pragma unroll
        for (int g = 1; g < 16; ++g) {
            const float4 v = psum[g][t];
            s.x += v.x; s.y += v.y; s.z += v.z; s.w += v.w;
        }
        sums[t] = s;
    }
    __syncthreads();

    // ---- write phase: out = total - x (x from LDS) ----
    const float4 s = sums[pg];
    float4* op = (float4*)(out + base);
    #pragma unroll
    for (int i = 0; i < 16; ++i) {
        const int c = i * 16 + cg;
        const float4 v = *(const float4*)&tile[c][pg * 4];
        op[(long long)c * (NC_HW / 4) + pg] =
            make_float4(s.x - v.x, s.y - v.y, s.z - v.z, s.w - v.w);
    }
}

extern "C" void kernel_launch(void* const* d_in, const int* in_sizes, int n_in,
                              void* d_out, int out_size, void* d_ws, size_t ws_size,
                              hipStream_t stream) {
    const float* x = (const float*)d_in[0];
    float* out = (float*)d_out;

    const int B = in_sizes[0] / (NC_C * NC_HW);      // 16
    const int grid = B * (NC_HW / NC_POS);           // 16 * 256 = 4096 blocks

    neighbour_channels_kernel<<<grid, NC_NT, 0, stream>>>(x, out);
}

// Round 2
// 424.039 us; speedup vs baseline: 1.0094x; 1.0094x over previous
//
#include <hip/hip_runtime.h>

// NeighbourChannels: out[b,c,hw] = (sum_c' x[b,c',hw]) - x[b,c,hw]
// x: fp32 [B=16, C=256, H=128, W=128], HW = 16384.
//
// Register-resident single pass:
//  - 1024 threads/block = 16 waves; wave w = channel group w (cg = t>>6),
//    lane = float4 position (pg = t&63). Every wave-load instruction reads
//    1 KiB contiguous from one channel row -> perfect coalescing.
//  - Each thread holds its 16 channel values in v[16] (64 VGPRs), so each
//    element is read from HBM exactly once and written exactly once
//    (512 MiB total, the roofline minimum).
//  - LDS only for the 16-way cross-wave channel-sum reduce (17 KiB).

#define NC_C    256
#define NC_HW   16384
#define NC_HW4  (NC_HW / 4)   // 4096 float4 per channel row
#define NC_POS4 64            // float4 positions per block (= wave width)
#define NC_NT   1024          // 16 waves
#define NC_CPT  16            // channels per thread = C / 16 waves

__global__ __launch_bounds__(NC_NT, 1)
void neighbour_channels_kernel(const float4* __restrict__ x4,
                               float4* __restrict__ out4) {
    __shared__ float4 psum[16][NC_POS4];  // [channel-group][pos] partials, 16 KiB
    __shared__ float4 sums[NC_POS4];      // per-pos channel totals, 1 KiB

    const int t  = threadIdx.x;
    const int pg = t & 63;                // lane within wave = float4 position
    const int cg = t >> 6;                // wave index = channel group 0..15

    // grid = B * (NC_HW4 / NC_POS4) = B * 64 blocks
    const int b     = blockIdx.x >> 6;
    const int chunk = blockIdx.x & 63;
    // 32-bit indexing: max element offset 2^24 float4 (2^28 bytes) < 2^31.
    const int base = b * (NC_C * NC_HW4) + chunk * NC_POS4 + pg;

    // ---- load phase: 16 independent contiguous 1 KiB wave-loads ----
    float4 v[NC_CPT];
    #pragma unroll
    for (int i = 0; i < NC_CPT; ++i) {
        const int c = cg * NC_CPT + i;
        v[i] = x4[base + c * NC_HW4];
    }

    // ---- per-thread partial channel sum ----
    float4 acc = make_float4(0.f, 0.f, 0.f, 0.f);
    #pragma unroll
    for (int i = 0; i < NC_CPT; ++i) {
        acc.x += v[i].x; acc.y += v[i].y; acc.z += v[i].z; acc.w += v[i].w;
    }
    psum[cg][pg] = acc;
    __syncthreads();

    // ---- reduce 16 channel-group partials per position (1 wave active) ----
    if (t < NC_POS4) {
        float4 s = psum[0][t];
        #pragma unroll
        for (int g = 1; g < 16; ++g) {
            const float4 p = psum[g][t];
            s.x += p.x; s.y += p.y; s.z += p.z; s.w += p.w;
        }
        sums[t] = s;
    }
    __syncthreads();

    // ---- write phase: out = total - x, from registers ----
    const float4 s = sums[pg];
    #pragma unroll
    for (int i = 0; i < NC_CPT; ++i) {
        const int c = cg * NC_CPT + i;
        out4[base + c * NC_HW4] =
            make_float4(s.x - v[i].x, s.y - v[i].y, s.z - v[i].z, s.w - v[i].w);
    }
}

extern "C" void kernel_launch(void* const* d_in, const int* in_sizes, int n_in,
                              void* d_out, int out_size, void* d_ws, size_t ws_size,
                              hipStream_t stream) {
    const float4* x4  = (const float4*)d_in[0];
    float4* out4      = (float4*)d_out;

    const int B    = in_sizes[0] / (NC_C * NC_HW);   // 16
    const int grid = B * (NC_HW4 / NC_POS4);         // 16 * 64 = 1024 blocks

    neighbour_channels_kernel<<<grid, NC_NT, 0, stream>>>(x4, out4);
}